// Round 1
// baseline (325.232 us; speedup 1.0000x reference)
//
#include <hip/hip_runtime.h>

#define BB 128
#define CC 272
#define TT 1024
#define DD 270
#define KK 32
#define NKC 9              // c-chunks of 32 (C padded to 288)
#define NMT 17             // d-tiles of 16 (D padded to 272)
#define MP 272
#define WBYTES (NKC * NMT * 64 * 16)   // 156,672 B

typedef __attribute__((ext_vector_type(8))) short s16x8;
typedef __attribute__((ext_vector_type(4))) float f32x4;

__device__ __forceinline__ unsigned short f2bf(float f) {
  unsigned int u = __builtin_bit_cast(unsigned int, f);
  u += 0x7fffu + ((u >> 16) & 1u);   // round-to-nearest-even
  return (unsigned short)(u >> 16);
}

// ---------------- Kernel 1: partial A[d][c], 4-way k-split ----------------
// A[d,c] = sum_{k,l} z_re[d,k,l]*cos(2pi(k x_c + l y_c)) + z_im[d,k,l]*sin(...)
// block (d, p): k in [8p, 8p+8). atomicAdd partial into zero-initialized A.
__global__ __launch_bounds__(288) void phaseA_kernel(
    const float* __restrict__ loc, const float* __restrict__ z_re,
    const float* __restrict__ z_im, float* __restrict__ A) {
  const int d = blockIdx.x;
  const int p = blockIdx.y;          // k-part 0..3
  const int c = threadIdx.x;
  if (c >= CC) return;
  const float TWO_PI = 6.28318530717958647692f;
  float x = loc[2 * c], y = loc[2 * c + 1];
  float sx, cx, sy, cyv;
  sincosf(TWO_PI * x, &sx, &cx);
  sincosf(TWO_PI * y, &sy, &cyv);
  float cl[KK], sl[KK];
  cl[0] = 1.f; sl[0] = 0.f;
#pragma unroll
  for (int l = 1; l < KK; ++l) {
    cl[l] = cl[l - 1] * cyv - sl[l - 1] * sy;
    sl[l] = sl[l - 1] * cyv + cl[l - 1] * sy;
  }
  const int k0 = p * 8;
  float sk, ck;
  sincosf(TWO_PI * (float)k0 * x, &sk, &ck);   // exact-ish start of rotation
  const float* zr = z_re + (size_t)d * (KK * KK) + k0 * KK;
  const float* zi = z_im + (size_t)d * (KK * KK) + k0 * KK;
  float acc = 0.f;
  for (int k = 0; k < 8; ++k) {
    float s_rc = 0.f, s_rs = 0.f, s_ic = 0.f, s_is = 0.f;
#pragma unroll
    for (int l = 0; l < KK; ++l) {
      float vr = zr[k * KK + l];   // wave-uniform -> scalar loads
      float vi = zi[k * KK + l];
      s_rc += vr * cl[l];
      s_rs += vr * sl[l];
      s_ic += vi * cl[l];
      s_is += vi * sl[l];
    }
    acc += ck * (s_rc + s_is) + sk * (s_ic - s_rs);
    float nck = ck * cx - sk * sx;
    sk = sk * cx + ck * sx;
    ck = nck;
  }
  atomicAdd(&A[d * CC + c], acc);
}

// ---------------- Kernel 2: row softmax -> bf16 w, MFMA-fragment layout ---
// w fragment layout: frag (kc, mt) occupies 1024 B: [lane 0..63][8 bf16].
// Lane l = hi*16 + m holds w[mt*16 + m][kc*32 + hi*8 + j], j = 0..7 — i.e.
// exactly the A-operand register layout of mfma_f32_16x16x32_bf16, so the
// GEMM reads each fragment as ONE coalesced 1 KB global_load_dwordx4/wave.
// Rows d>=270 and cols c>=272 are zeros (M/K padding).
__global__ __launch_bounds__(64) void softmax_kernel(
    const float* __restrict__ A, unsigned short* __restrict__ wb) {
  const int d = blockIdx.x;   // 0..271
  const int lane = threadIdx.x;
  const bool live = (d < DD);
  float v[5];
  float inv = 0.f;
  if (live) {
    float m = -3.0e38f;
#pragma unroll
    for (int j = 0; j < 5; ++j) {
      int cidx = lane + 64 * j;
      v[j] = (cidx < CC) ? A[(size_t)d * CC + cidx] : -3.0e38f;
      m = fmaxf(m, v[j]);
    }
#pragma unroll
    for (int off = 32; off >= 1; off >>= 1) m = fmaxf(m, __shfl_xor(m, off, 64));
    float s = 0.f;
#pragma unroll
    for (int j = 0; j < 5; ++j) {
      int cidx = lane + 64 * j;
      v[j] = (cidx < CC) ? expf(v[j] - m) : 0.f;
      s += v[j];
    }
#pragma unroll
    for (int off = 32; off >= 1; off >>= 1) s += __shfl_xor(s, off, 64);
    inv = 1.f / s;
  }
  const int mt = d >> 4, mrow = d & 15;
#pragma unroll
  for (int j = 0; j < 5; ++j) {
    int kk = lane + 64 * j;      // column index incl. padding
    if (kk < NKC * KK) {
      unsigned short val = 0;
      if (live && kk < CC) val = f2bf(v[j] * inv);
      int kc = kk >> 5, hi = (kk >> 3) & 3, jj = kk & 7;
      wb[((size_t)(kc * NMT + mt) << 9) + (((hi << 4) | mrow) << 3) + jj] = val;
    }
  }
}

// ---------------- Kernel 3: out[b,d,t] = sum_c w[d,c] * X[b,c,t] ----------
// 256-thread block = 4 waves. Block covers (b, 64-t tile); wave dw owns
// m-tiles {dw, dw+4, dw+8, dw+12 (+16 for dw==0)} x 4 n-frags (64 t).
// NO LDS, NO barriers: A-frags are coalesced 1 KB dwordx4 reads from the
// L2-resident (156 KB) pre-fragmented w buffer; B comes from X via scalar
// loads (64 B segments). Both A and X are software-prefetched 1 chunk ahead.
// Each A-read now feeds 4 MFMAs (vs 1 before) and there is no LDS port
// serialization and no 1-block/CU LDS cap.
__global__ __launch_bounds__(256, 2) void gemm_kernel(
    const float* __restrict__ X, const unsigned short* __restrict__ wb,
    float* __restrict__ out) {
  const int bid = blockIdx.x;
  const int b = bid >> 4;
  const int t0 = (bid & 15) << 6;     // 64-wide t tile
  const int tid = threadIdx.x;
  const int lane = tid & 63;
  const int dw = tid >> 6;            // d-group 0..3 (wave-uniform)
  const int q = lane >> 4;            // k-subgroup 0..3
  const int r16 = lane & 15;
  const bool has5 = (dw == 0);        // dw0 also owns m-tile 16

  f32x4 acc[5][4];
#pragma unroll
  for (int i = 0; i < 5; ++i)
#pragma unroll
    for (int f = 0; f < 4; ++f) acc[i][f] = (f32x4){0.f, 0.f, 0.f, 0.f};

  const unsigned short* wf = wb + (size_t)lane * 8;
  const float* Xb = X + (size_t)b * (CC * TT) + t0 + r16;
  const int csub = q << 3;

  s16x8 a_cur[5], a_nxt[5];
  float xf[32], xn[32];               // [f*8 + j]

  // ---- prefetch chunk 0 ----
#pragma unroll
  for (int i = 0; i < 4; ++i)
    a_cur[i] = *(const s16x8*)(wf + ((size_t)(dw + (i << 2)) << 9));
  if (has5) a_cur[4] = *(const s16x8*)(wf + ((size_t)16 << 9));
#pragma unroll
  for (int f = 0; f < 4; ++f)
#pragma unroll
    for (int j = 0; j < 8; ++j)
      xf[f * 8 + j] = Xb[(size_t)(csub + j) * TT + (f << 4)];   // c <= 31

#pragma unroll
  for (int kc = 0; kc < NKC; ++kc) {
    // ---- prefetch chunk kc+1 (A from L2, X from HBM) ----
    if (kc < NKC - 1) {
      const int cb = (kc + 1) * KK + csub;
#pragma unroll
      for (int i = 0; i < 4; ++i)
        a_nxt[i] = *(const s16x8*)(wf + ((size_t)((kc + 1) * NMT + dw + (i << 2)) << 9));
      if (has5)
        a_nxt[4] = *(const s16x8*)(wf + ((size_t)((kc + 1) * NMT + 16) << 9));
#pragma unroll
      for (int f = 0; f < 4; ++f)
#pragma unroll
        for (int j = 0; j < 8; ++j)
          xn[f * 8 + j] = (cb + j < CC) ? Xb[(size_t)(cb + j) * TT + (f << 4)] : 0.f;
    }
    // ---- convert B frags to packed bf16 ----
    union { unsigned int u[4]; s16x8 v; } bf[4];
#pragma unroll
    for (int f = 0; f < 4; ++f)
#pragma unroll
      for (int p = 0; p < 4; ++p)
        bf[f].u[p] = (unsigned int)f2bf(xf[f * 8 + 2 * p]) |
                     ((unsigned int)f2bf(xf[f * 8 + 2 * p + 1]) << 16);
    // ---- MFMA: each A-frag feeds 4 MFMAs ----
#pragma unroll
    for (int i = 0; i < 4; ++i)
#pragma unroll
      for (int f = 0; f < 4; ++f)
        acc[i][f] = __builtin_amdgcn_mfma_f32_16x16x32_bf16(a_cur[i], bf[f].v, acc[i][f], 0, 0, 0);
    if (has5) {
#pragma unroll
      for (int f = 0; f < 4; ++f)
        acc[4][f] = __builtin_amdgcn_mfma_f32_16x16x32_bf16(a_cur[4], bf[f].v, acc[4][f], 0, 0, 0);
    }
    // ---- rotate double buffers (renamed away by full unroll) ----
#pragma unroll
    for (int i = 0; i < 5; ++i) a_cur[i] = a_nxt[i];
#pragma unroll
    for (int v2 = 0; v2 < 32; ++v2) xf[v2] = xn[v2];
  }

  // ---- epilogue: D row = mt*16 + q*4 + r, col t = t0 + f*16 + r16 ----
  float* op = out + (size_t)b * (DD * TT) + t0 + r16;
#pragma unroll
  for (int i = 0; i < 4; ++i) {
    const int mtb = (dw + (i << 2)) << 4;   // <= 240, always < DD
#pragma unroll
    for (int f = 0; f < 4; ++f)
#pragma unroll
      for (int r = 0; r < 4; ++r)
        op[(size_t)(mtb + q * 4 + r) * TT + (f << 4)] = acc[i][f][r];
  }
  if (has5) {
#pragma unroll
    for (int f = 0; f < 4; ++f)
#pragma unroll
      for (int r = 0; r < 4; ++r) {
        const int drow = 256 + q * 4 + r;
        if (drow < DD) op[(size_t)drow * TT + (f << 4)] = acc[4][f][r];
      }
  }
}

extern "C" void kernel_launch(void* const* d_in, const int* in_sizes, int n_in,
                              void* d_out, int out_size, void* d_ws, size_t ws_size,
                              hipStream_t stream) {
  const float* X = (const float*)d_in[0];
  const float* loc = (const float*)d_in[1];
  const float* z_re = (const float*)d_in[2];
  const float* z_im = (const float*)d_in[3];
  float* out = (float*)d_out;

  float* A = (float*)d_ws;                                        // 293,760 B
  unsigned short* wbf = (unsigned short*)((char*)d_ws + 294912);  // 156,672 B

  hipMemsetAsync(A, 0, DD * CC * sizeof(float), stream);
  phaseA_kernel<<<dim3(DD, 4), 288, 0, stream>>>(loc, z_re, z_im, A);
  softmax_kernel<<<MP, 64, 0, stream>>>(A, wbf);
  gemm_kernel<<<BB * (TT / 64), 256, 0, stream>>>(X, wbf, out);
}

// Round 2
// 318.485 us; speedup vs baseline: 1.0212x; 1.0212x over previous
//
#include <hip/hip_runtime.h>

#define BB 128
#define CC 272
#define TT 1024
#define DD 270
#define KK 32
#define NKC 9              // c-chunks of 32 (C padded to 288)
#define NMT 17             // d-tiles of 16 (D padded to 272)
#define MP 272

typedef __attribute__((ext_vector_type(8))) short s16x8;
typedef __attribute__((ext_vector_type(4))) float f32x4;

__device__ __forceinline__ unsigned short f2bf(float f) {
  unsigned int u = __builtin_bit_cast(unsigned int, f);
  u += 0x7fffu + ((u >> 16) & 1u);   // round-to-nearest-even
  return (unsigned short)(u >> 16);
}

// ---------------- Kernel 1: partial A[d][c], 4-way k-split ----------------
__global__ __launch_bounds__(288) void phaseA_kernel(
    const float* __restrict__ loc, const float* __restrict__ z_re,
    const float* __restrict__ z_im, float* __restrict__ A) {
  const int d = blockIdx.x;
  const int p = blockIdx.y;          // k-part 0..3
  const int c = threadIdx.x;
  if (c >= CC) return;
  const float TWO_PI = 6.28318530717958647692f;
  float x = loc[2 * c], y = loc[2 * c + 1];
  float sx, cx, sy, cyv;
  sincosf(TWO_PI * x, &sx, &cx);
  sincosf(TWO_PI * y, &sy, &cyv);
  float cl[KK], sl[KK];
  cl[0] = 1.f; sl[0] = 0.f;
#pragma unroll
  for (int l = 1; l < KK; ++l) {
    cl[l] = cl[l - 1] * cyv - sl[l - 1] * sy;
    sl[l] = sl[l - 1] * cyv + cl[l - 1] * sy;
  }
  const int k0 = p * 8;
  float sk, ck;
  sincosf(TWO_PI * (float)k0 * x, &sk, &ck);
  const float* zr = z_re + (size_t)d * (KK * KK) + k0 * KK;
  const float* zi = z_im + (size_t)d * (KK * KK) + k0 * KK;
  float acc = 0.f;
  for (int k = 0; k < 8; ++k) {
    float s_rc = 0.f, s_rs = 0.f, s_ic = 0.f, s_is = 0.f;
#pragma unroll
    for (int l = 0; l < KK; ++l) {
      float vr = zr[k * KK + l];   // wave-uniform -> scalar loads
      float vi = zi[k * KK + l];
      s_rc += vr * cl[l];
      s_rs += vr * sl[l];
      s_ic += vi * cl[l];
      s_is += vi * sl[l];
    }
    acc += ck * (s_rc + s_is) + sk * (s_ic - s_rs);
    float nck = ck * cx - sk * sx;
    sk = sk * cx + ck * sx;
    ck = nck;
  }
  atomicAdd(&A[d * CC + c], acc);
}

// ---------------- Kernel 2: row softmax -> bf16 w, MFMA-fragment layout ---
// Frag (kc, mt) = 1024 B: lane l = hi*16 + m holds w[mt*16+m][kc*32+hi*8+j],
// j=0..7 — exactly the A-operand layout of mfma_f32_16x16x32_bf16. Pads zero.
__global__ __launch_bounds__(64) void softmax_kernel(
    const float* __restrict__ A, unsigned short* __restrict__ wb) {
  const int d = blockIdx.x;   // 0..271
  const int lane = threadIdx.x;
  const bool live = (d < DD);
  float v[5];
  float inv = 0.f;
  if (live) {
    float m = -3.0e38f;
#pragma unroll
    for (int j = 0; j < 5; ++j) {
      int cidx = lane + 64 * j;
      v[j] = (cidx < CC) ? A[(size_t)d * CC + cidx] : -3.0e38f;
      m = fmaxf(m, v[j]);
    }
#pragma unroll
    for (int off = 32; off >= 1; off >>= 1) m = fmaxf(m, __shfl_xor(m, off, 64));
    float s = 0.f;
#pragma unroll
    for (int j = 0; j < 5; ++j) {
      int cidx = lane + 64 * j;
      v[j] = (cidx < CC) ? expf(v[j] - m) : 0.f;
      s += v[j];
    }
#pragma unroll
    for (int off = 32; off >= 1; off >>= 1) s += __shfl_xor(s, off, 64);
    inv = 1.f / s;
  }
  const int mt = d >> 4, mrow = d & 15;
#pragma unroll
  for (int j = 0; j < 5; ++j) {
    int kk = lane + 64 * j;      // column index incl. padding
    if (kk < NKC * KK) {
      unsigned short val = 0;
      if (live && kk < CC) val = f2bf(v[j] * inv);
      int kc = kk >> 5, hi = (kk >> 3) & 3, jj = kk & 7;
      wb[((size_t)(kc * NMT + mt) << 9) + (((hi << 4) | mrow) << 3) + jj] = val;
    }
  }
}

// ---------------- Kernel 3: out[b,d,t] = sum_c w[d,c] * X[b,c,t] ----------
// 256 threads = 4 waves (d-groups), t-tile 64. X staged through a 4-deep
// 8 KB LDS ring via global_load_lds (counted vmcnt, never drained to 0);
// A-frags register-prefetched from the L2-resident w buffer. XOR-swizzled
// X layout: LDS[c][t ^ ((c>>3)&3)<<4] -> 2-way-max bank conflicts (free).
// Uniform per-wave VMEM counts (2 stage + 5 A per iter) keep the asm vmcnt
// literals exact for every wave; counts are fence-window-robust.
__global__ __launch_bounds__(256, 2) void gemm_kernel(
    const float* __restrict__ X, const unsigned short* __restrict__ wb,
    float* __restrict__ out) {
  __shared__ float xs[4][KK * 64];            // 4 x 8 KB ring
  const int bid = blockIdx.x;
  const int b = bid >> 4;
  const int t0 = (bid & 15) << 6;             // 64-wide t tile
  const int tid = threadIdx.x;
  const int lane = tid & 63;
  const int dw = tid >> 6;                    // d-group 0..3 (wave-uniform)
  const int q = lane >> 4;                    // k-subgroup 0..3
  const int r16 = lane & 15;

  const unsigned short* wf = wb + (size_t)lane * 8;
  const float* Xb = X + (size_t)b * (CC * TT) + t0;

  // stage params: thread handles 16B units idx = tid, tid+256
  int scl[2], stf[2];
#pragma unroll
  for (int r = 0; r < 2; ++r) {
    int idx = tid + (r << 8);
    scl[r] = idx >> 4;                                   // c_local 0..31
    stf[r] = ((idx & 15) << 2) ^ (((idx >> 7) & 3) << 4); // swizzled t-off
  }

#define STAGE(KC_, BUF_) do {                                              \
    const int kcs_ = (KC_);                                                \
    float* dstb_ = &xs[(BUF_)][0];                                         \
    _Pragma("unroll")                                                      \
    for (int r_ = 0; r_ < 2; ++r_) {                                       \
      int idx_ = tid + (r_ << 8);                                          \
      int cg_ = kcs_ * KK + scl[r_];                                       \
      if (cg_ > CC - 1) cg_ = CC - 1; /* tail pad: w rows are zero */      \
      const float* src_ = Xb + (size_t)cg_ * TT + stf[r_];                 \
      __builtin_amdgcn_global_load_lds(                                    \
          (const __attribute__((address_space(1))) unsigned int*)src_,     \
          (__attribute__((address_space(3))) unsigned int*)(dstb_ + idx_ * 4), \
          16, 0, 0);                                                       \
    }                                                                      \
  } while (0)

  // m-tiles per wave: {dw, dw+4, dw+8, dw+12, 16} (tile 16 loaded by all
  // waves for uniform vmcnt; only dw==0 stores it)
  int mti[5] = {dw, dw + 4, dw + 8, dw + 12, 16};

  f32x4 acc[5][4];
#pragma unroll
  for (int i = 0; i < 5; ++i)
#pragma unroll
    for (int f = 0; f < 4; ++f) acc[i][f] = (f32x4){0.f, 0.f, 0.f, 0.f};

  // loop-invariant swizzled t' per frag
  int tq[4];
#pragma unroll
  for (int f = 0; f < 4; ++f) tq[f] = ((f << 4) + r16) ^ (q << 4);
  const int crow = q << 3;

  s16x8 a_cur[5], a_nxt[5];

  // ---- prologue: stage(0) | fence | stage(1), stage(2), A(0) ----
  STAGE(0, 0);
  asm volatile("" ::: "memory");   // pin stage(0) oldest for the vmcnt(11)
  STAGE(1, 1);
  STAGE(2, 2);
#pragma unroll
  for (int i = 0; i < 5; ++i)
    a_cur[i] = *(const s16x8*)(wf + ((size_t)mti[i] << 9));

#pragma unroll
  for (int kc = 0; kc < NKC; ++kc) {
    // s0: issue stage kc+3 (dummy re-stage of chunk 8 in the tail; its
    // ring slot (kc+3)&3 was last read at iter kc-1, already barriered)
    {
      const int kcs = (kc + 3 < NKC) ? kc + 3 : NKC - 1;
      STAGE(kcs, (kc + 3) & 3);
    }
    if (kc == 0) {
      // window since prologue fence: st1(2)+st2(2)+A0(5)+st3(2) = 11
      asm volatile("s_waitcnt vmcnt(11)" ::: "memory");
    }
    // barrier-1: all waves' stage(kc) landed (kc>0: guaranteed by each
    // wave's previous-iteration vmcnt(7))
    __builtin_amdgcn_s_barrier();
    asm volatile("" ::: "memory");

    // ds_read chunk kc (32 floats/lane, 2-way-max banks)
    float tmp[32];
    {
      const float* bufp = &xs[kc & 3][0];
#pragma unroll
      for (int f = 0; f < 4; ++f)
#pragma unroll
        for (int j = 0; j < 8; ++j)
          tmp[f * 8 + j] = bufp[(crow + j) * 64 + tq[f]];
    }
    // barrier-2: all waves done reading buf[kc&3]; next iter may overwrite
    asm volatile("s_waitcnt lgkmcnt(0)" ::: "memory");
    __builtin_amdgcn_s_barrier();

    // A-prefetch chunk kc+1 (dummy reload of chunk 8 at kc==8)
    {
      const int kca = (kc + 1 < NKC) ? kc + 1 : NKC - 1;
#pragma unroll
      for (int i = 0; i < 5; ++i)
        a_nxt[i] = *(const s16x8*)(wf + ((size_t)(kca * NMT + mti[i]) << 9));
    }
    // counted wait: newest window = stage(kc+3)[2] + A(kc+1)[5] = 7.
    // Forces a_cur (=A(kc)) and stage(kc+1) complete; ring stays 2-3 deep.
    asm volatile("s_waitcnt vmcnt(7)" ::: "memory");

    // convert + MFMA
    union { unsigned int u[4]; s16x8 v; } bf[4];
#pragma unroll
    for (int f = 0; f < 4; ++f)
#pragma unroll
      for (int p = 0; p < 4; ++p)
        bf[f].u[p] = (unsigned int)f2bf(tmp[f * 8 + 2 * p]) |
                     ((unsigned int)f2bf(tmp[f * 8 + 2 * p + 1]) << 16);
#pragma unroll
    for (int i = 0; i < 5; ++i)
#pragma unroll
      for (int f = 0; f < 4; ++f)
        acc[i][f] = __builtin_amdgcn_mfma_f32_16x16x32_bf16(a_cur[i], bf[f].v, acc[i][f], 0, 0, 0);
#pragma unroll
    for (int i = 0; i < 5; ++i) a_cur[i] = a_nxt[i];
  }
#undef STAGE

  // ---- epilogue: D row = mt*16 + q*4 + r, col t = t0 + f*16 + r16 ----
  float* op = out + (size_t)b * (DD * TT) + t0 + r16;
#pragma unroll
  for (int i = 0; i < 4; ++i) {
    const int mtb = (dw + (i << 2)) << 4;   // <= 240+15 < DD
#pragma unroll
    for (int f = 0; f < 4; ++f)
#pragma unroll
      for (int r = 0; r < 4; ++r)
        op[(size_t)(mtb + q * 4 + r) * TT + (f << 4)] = acc[i][f][r];
  }
  if (dw == 0) {
#pragma unroll
    for (int f = 0; f < 4; ++f)
#pragma unroll
      for (int r = 0; r < 4; ++r) {
        const int drow = 256 + q * 4 + r;
        if (drow < DD) op[(size_t)drow * TT + (f << 4)] = acc[4][f][r];
      }
  }
}

extern "C" void kernel_launch(void* const* d_in, const int* in_sizes, int n_in,
                              void* d_out, int out_size, void* d_ws, size_t ws_size,
                              hipStream_t stream) {
  const float* X = (const float*)d_in[0];
  const float* loc = (const float*)d_in[1];
  const float* z_re = (const float*)d_in[2];
  const float* z_im = (const float*)d_in[3];
  float* out = (float*)d_out;

  float* A = (float*)d_ws;                                        // 293,760 B
  unsigned short* wbf = (unsigned short*)((char*)d_ws + 294912);  // 156,672 B

  hipMemsetAsync(A, 0, DD * CC * sizeof(float), stream);
  phaseA_kernel<<<dim3(DD, 4), 288, 0, stream>>>(loc, z_re, z_im, A);
  softmax_kernel<<<MP, 64, 0, stream>>>(A, wbf);
  gemm_kernel<<<BB * (TT / 64), 256, 0, stream>>>(X, wbf, out);
}